// Round 10
// baseline (337.718 us; speedup 1.0000x reference)
//
#include <hip/hip_runtime.h>
#include <math.h>

#define VIF_EPS       1e-10f
#define SIGMA_NSQ     2.0f
#define SIGMA_MAX_INV (4.0f / (255.0f * 255.0f))
#define GAIN_LIMIT    100.0f

// jnp.pad mode='reflect' (no edge duplication). Overshoot < dim, single reflection suffices.
__device__ __forceinline__ int reflect_idx(int i, int n) {
    i = (i < 0) ? -i : i;
    i = (i >= n) ? (2 * n - 2 - i) : i;
    return i;
}

// Reference: sigma=N/5; g=exp(-x^2/(2 sigma^2)); win=outer(g,g)/sum -> separable gn = g/sum(g).
// Thread-0 + LDS broadcast (R7-proven register footprint; R9's all-lane expf raised VGPR 68->92).
template <int N>
__device__ __forceinline__ void compute_weights(float* wts) {
    if (threadIdx.x == 0) {
        const float sigma = (float)N / 5.0f;
        const float denom = 2.0f * sigma * sigma;
        float s = 0.0f;
        for (int i = 0; i < N; ++i) {
            float x = (float)i - (float)(N - 1) * 0.5f;
            float g = expf(-(x * x) / denom);
            wts[i] = g;
            s += g;
        }
        for (int i = 0; i < N; ++i) wts[i] = wts[i] / s;
    }
}

constexpr int tile_w(int N) { return (128 - (N - 1)) & ~3; }  // 17->112, 9->120, 5/3->124
constexpr int cdiv(int a, int b) { return (a + b - 1) / b; }

// ---- pyramid constants ----
constexpr int B_ = 4;
constexpr int H0_ = 1080, W0_ = 1920;
constexpr int H1_ = 540,  W1_ = 960;
constexpr int H2_ = 270,  W2_ = 480;
constexpr int H3_ = 135,  W3_ = 240;

constexpr int SX0 = cdiv(W0_, tile_w(17)), SY0 = cdiv(H0_, 8), N0_ = SX0 * SY0;  // 18x135
constexpr int SX1 = cdiv(W1_, tile_w(9)),  SY1 = cdiv(H1_, 8), N1_ = SX1 * SY1;  // 8x68
constexpr int SX2 = cdiv(W2_, tile_w(5)),  SY2 = cdiv(H2_, 8), N2_ = SX2 * SY2;  // 4x34
constexpr int SX3 = cdiv(W3_, tile_w(3)),  SY3 = cdiv(H3_, 8), N3_ = SX3 * SY3;  // 2x17

constexpr int DGX1 = W1_ / 120, ND1_ = DGX1 * cdiv(H1_, 8);  // 544
constexpr int DGX2 = W2_ / 120, ND2_ = DGX2 * cdiv(H2_, 8);  // 136
constexpr int DGX3 = W3_ / 120, ND3_ = DGX3 * cdiv(H3_, 8);  // 34

// ---- static shared layouts ----
template <int N>
struct StatsSmem {
    float v[5][8][132];   // row stride 528 B = 33*16 -> float4-clean
    float wts[N];
    float rsum[8];
};
template <int N>
struct DownSmem {
    float vb[2][8][252];
    float wts[N];
};

// ---------------- stats body (vertical-first separable VIF; R7-proven, atomic finish) --------
// bx flattened Y-MAJOR (ytile = bx % sy) for L2 reuse of vertical halos.
// VGPR discipline (~68): NO min-waves bound (R3 spill), 4-wide phase 2 (R5), no
// cross-phase unions (R8), no KY loop / per-thread expf (R9). Keep it.
template <int N>
__device__ __forceinline__ void stats_body(
    StatsSmem<N>& sm, const float* __restrict__ refp, const float* __restrict__ distp,
    int h, int w, float shift, double* __restrict__ accND,
    int sy, int bx, int b) {
    constexpr int P   = (N - 1) / 2;
    constexpr int VC  = 128;
    constexpr int TW  = tile_w(N);
    constexpr int TH  = 8;
    constexpr int Q   = 4;
    constexpr int LR  = Q + 2 * P;
    constexpr int XG  = TW / 4;
    constexpr int F4  = (N + 6) / 4;

    const int tid = threadIdx.x;
    const int ytile = bx % sy;
    const int xtile = bx / sy;
    const int x0 = xtile * TW;
    const int y0 = ytile * TH;

    compute_weights<N>(sm.wts);
    __syncthreads();

    float wr[N];
#pragma unroll
    for (int j = 0; j < N; ++j) wr[j] = sm.wts[j];

    // ---- Phase 1: vertical conv from global ----
    {
        const int c = tid & (VC - 1);
        const int g = tid >> 7;
        const int gx = reflect_idx(x0 + c - P, w);
        const float* rb = refp  + (size_t)b * h * w + gx;
        const float* db = distp + (size_t)b * h * w + gx;

        float acc[5][Q];
#pragma unroll
        for (int ch = 0; ch < 5; ++ch)
#pragma unroll
            for (int q = 0; q < Q; ++q) acc[ch][q] = 0.f;

        auto acc_push = [&](int i, float r, float d) {
            float p2 = r * r, p3 = d * d, p4 = r * d;
#pragma unroll
            for (int q = 0; q < Q; ++q) {
                int j = i - q;
                if (j >= 0 && j < N) {
                    float wj = wr[j];
                    acc[0][q] += wj * r;
                    acc[1][q] += wj * d;
                    acc[2][q] += wj * p2;
                    acc[3][q] += wj * p3;
                    acc[4][q] += wj * p4;
                }
            }
        };

        const int rowlo = y0 + g * Q - P;
        if (rowlo >= 0 && rowlo + LR <= h) {
            // Interior fast path (wave-uniform): pointer walk, no reflect per row.
            const float* pr = rb + (size_t)rowlo * w;
            const float* pd = db + (size_t)rowlo * w;
#pragma unroll
            for (int i = 0; i < LR; ++i) {
                float r = pr[0] - shift;
                float d = pd[0] - shift;
                pr += w; pd += w;
                acc_push(i, r, d);
            }
        } else {
#pragma unroll
            for (int i = 0; i < LR; ++i) {
                int gy = reflect_idx(rowlo + i, h);
                float r = rb[(size_t)gy * w] - shift;
                float d = db[(size_t)gy * w] - shift;
                acc_push(i, r, d);
            }
        }
#pragma unroll
        for (int ch = 0; ch < 5; ++ch)
#pragma unroll
            for (int q = 0; q < Q; ++q)
                sm.v[ch][g * Q + q][c] = acc[ch][q];
    }
    __syncthreads();

    // ---- Phase 2: horizontal conv + VIF math (4 outputs/thread) ----
    float num_v = 0.f, den_v = 0.f;
    {
        const int xg  = tid & 31;
        const int row = tid >> 5;
        if (xg < XG) {
            float mu[5][4];
#pragma unroll
            for (int ch = 0; ch < 5; ++ch) {
                float win[F4 * 4];
                const float4* s4 = (const float4*)&sm.v[ch][row][xg * 4];
#pragma unroll
                for (int f = 0; f < F4; ++f) {
                    float4 t = s4[f];
                    win[4 * f + 0] = t.x; win[4 * f + 1] = t.y;
                    win[4 * f + 2] = t.z; win[4 * f + 3] = t.w;
                }
#pragma unroll
                for (int q = 0; q < 4; ++q) {
                    float a = 0.f;
#pragma unroll
                    for (int j = 0; j < N; ++j) a += wr[j] * win[q + j];
                    mu[ch][q] = a;
                }
            }
            const int gy = y0 + row;
#pragma unroll
            for (int q = 0; q < 4; ++q) {
                int gx = x0 + xg * 4 + q;
                if (gx < w && gy < h) {
                    float mu1 = mu[0][q], mu2 = mu[1][q];
                    float s1  = fmaxf(0.f, mu[2][q] - mu1 * mu1);
                    float s2  = fmaxf(0.f, mu[3][q] - mu2 * mu2);
                    float s12 = mu[4][q] - mu1 * mu2;

                    float g  = s12 / (s1 + VIF_EPS);
                    float sv = s2 - g * s12;
                    if (s1 < VIF_EPS) { g = 0.f; sv = s2; s1 = 0.f; }
                    if (s2 < VIF_EPS) { g = 0.f; sv = 0.f; }
                    if (g  < 0.f)     { sv = s2; g = 0.f; }
                    if (sv <= VIF_EPS) sv = VIF_EPS;
                    g = fminf(g, GAIN_LIMIT);

                    float num_ar = __log2f(1.f + g * g * s1 / (sv + SIGMA_NSQ));
                    float den_ar = __log2f(1.f + s1 / SIGMA_NSQ);
                    if (s12 < 0.f) num_ar = 0.f;
                    if (s1 < SIGMA_NSQ) { num_ar = 1.f - s2 * SIGMA_MAX_INV; den_ar = 1.f; }
                    num_v += num_ar;
                    den_v += den_ar;
                }
            }
        }
    }

    // Block reduction, then ONE atomic pair per block (register-neutral vs partial write).
#pragma unroll
    for (int off = 32; off > 0; off >>= 1) {
        num_v += __shfl_down(num_v, off);
        den_v += __shfl_down(den_v, off);
    }
    const int wid = tid >> 6, lane = tid & 63;
    if (lane == 0) { sm.rsum[wid] = num_v; sm.rsum[4 + wid] = den_v; }
    __syncthreads();
    if (tid == 0) {
        float ns = sm.rsum[0] + sm.rsum[1] + sm.rsum[2] + sm.rsum[3];
        float ds = sm.rsum[4] + sm.rsum[5] + sm.rsum[6] + sm.rsum[7];
        atomicAdd(&accND[0], (double)ns);
        atomicAdd(&accND[1], (double)ds);
    }
}

// ---------------- downsample body: vertical-first, 120x8 output tile (R7-proven) ----------------
template <int N>
__device__ __forceinline__ void down_body(
    DownSmem<N>& sm, const float* __restrict__ rin, const float* __restrict__ din,
    float* __restrict__ rout, float* __restrict__ dout,
    int h, int w, int h2, int w2, float shift, int dgx, int bx, int b) {
    constexpr int P   = (N - 1) / 2;
    constexpr int TOW = 120, TOH = 8;
    constexpr int IC  = 2 * (TOW - 1) + N;
    constexpr int NR  = 2 * (TOH - 1) + N;
    constexpr int XGn = TOW / 8;
    constexpr int WL  = 14 + N;
    constexpr int F4n = (WL + 3) / 4;

    compute_weights<N>(sm.wts);
    __syncthreads();

    float wr[N];
#pragma unroll
    for (int j = 0; j < N; ++j) wr[j] = sm.wts[j];

    const int tid = threadIdx.x;
    const int xt  = bx % dgx;
    const int yt  = bx / dgx;
    const int x0  = xt * TOW;
    const int y0  = yt * TOH;

    // ---- Vertical decimating pass ----
    if (tid < IC) {
        const int gx = reflect_idx(2 * x0 - P + tid, w);
        const int rowlo = 2 * y0 - P;
        const bool interior = (rowlo >= 0) && (rowlo + NR <= h);
#pragma unroll
        for (int img = 0; img < 2; ++img) {
            const float* src = (img ? din : rin) + (size_t)b * h * w + gx;
            float rows[NR];
            if (interior) {
                const float* p = src + (size_t)rowlo * w;
#pragma unroll
                for (int i = 0; i < NR; ++i) { rows[i] = p[0] - shift; p += w; }
            } else {
#pragma unroll
                for (int i = 0; i < NR; ++i)
                    rows[i] = src[(size_t)reflect_idx(rowlo + i, h) * w] - shift;
            }
#pragma unroll
            for (int t = 0; t < TOH; ++t) {
                float a = 0.f;
#pragma unroll
                for (int j = 0; j < N; ++j) a += wr[j] * rows[2 * t + j];
                sm.vb[img][t][tid] = a;
            }
        }
    }
    __syncthreads();

    // ---- Horizontal decimating pass ----
    if (tid < 2 * TOH * XGn) {
        const int img = tid / (TOH * XGn);
        const int rem = tid - img * (TOH * XGn);
        const int row = rem / XGn;
        const int xg  = rem - row * XGn;

        float win[F4n * 4];
        const float4* s4 = (const float4*)&sm.vb[img][row][16 * xg];
#pragma unroll
        for (int f = 0; f < F4n; ++f) {
            float4 t = s4[f];
            win[4 * f + 0] = t.x; win[4 * f + 1] = t.y;
            win[4 * f + 2] = t.z; win[4 * f + 3] = t.w;
        }
        float o[8];
#pragma unroll
        for (int q = 0; q < 8; ++q) {
            float a = 0.f;
#pragma unroll
            for (int j = 0; j < N; ++j) a += wr[j] * win[2 * q + j];
            o[q] = a;
        }
        const int gy = y0 + row;
        if (gy < h2) {
            float* outp = (img ? dout : rout) + (size_t)b * h2 * w2
                        + (size_t)gy * w2 + x0 + 8 * xg;
            *(float4*)outp       = make_float4(o[0], o[1], o[2], o[3]);
            *(float4*)(outp + 4) = make_float4(o[4], o[5], o[6], o[7]);
        }
    }
}

// ---------------- kernels ----------------
// acc layout: 16 x double2 {num, den} indexed by (b*4 + scale); ticket u32 after.
template <int NS, int ND, int SCALE>
__global__ __launch_bounds__(256) void fused_kernel(
    const float* __restrict__ sref, const float* __restrict__ sdist,
    int sh, int sw, float sshift, double* __restrict__ acc, int sy,
    float* __restrict__ drout, float* __restrict__ ddout,
    int dh2, int dw2, int dgx, int nStats) {
    __shared__ union {
        StatsSmem<NS> s;
        DownSmem<ND>  d;
    } u;
    const int bx = blockIdx.x;
    const int b  = blockIdx.z;
    if (bx < nStats)
        stats_body<NS>(u.s, sref, sdist, sh, sw, sshift,
                       acc + 2 * (b * 4 + SCALE), sy, bx, b);
    else
        down_body<ND>(u.d, sref, sdist, drout, ddout, sh, sw, dh2, dw2, sshift, dgx,
                      bx - nStats, b);
}

// Final kernel: stats<3> + ticket; last block writes all 16 outputs.
template <int N>
__global__ __launch_bounds__(256) void final_kernel(
    const float* __restrict__ refp, const float* __restrict__ distp,
    int h, int w, double* __restrict__ acc, unsigned* __restrict__ ticket,
    int sy, int nTickets, float* __restrict__ out) {
    __shared__ StatsSmem<N> sm;
    const int b = blockIdx.z;
    stats_body<N>(sm, refp, distp, h, w, 0.0f,
                  acc + 2 * (b * 4 + 3), sy, blockIdx.x, b);
    if (threadIdx.x == 0) {
        __threadfence();
        unsigned old = atomicAdd(ticket, 1u);
        if (old == (unsigned)(nTickets - 1)) {
            for (int i = 0; i < 16; ++i) {
                double nv = __hip_atomic_load(&acc[2 * i],     __ATOMIC_RELAXED,
                                              __HIP_MEMORY_SCOPE_AGENT);
                double dv = __hip_atomic_load(&acc[2 * i + 1], __ATOMIC_RELAXED,
                                              __HIP_MEMORY_SCOPE_AGENT);
                out[i] = (float)(nv / dv);
            }
        }
    }
}

extern "C" void kernel_launch(void* const* d_in, const int* in_sizes, int n_in,
                              void* d_out, int out_size, void* d_ws, size_t ws_size,
                              hipStream_t stream) {
    const float* ref  = (const float*)d_in[0];
    const float* dist = (const float*)d_in[1];
    float* out = (float*)d_out;

    char*  ws  = (char*)d_ws;
    size_t off = 0;
    auto alloc = [&](size_t bytes) -> void* {
        void* p = ws + off;
        off += (bytes + 255) & ~(size_t)255;
        return p;
    };
    float* ref1  = (float*)alloc((size_t)B_ * H1_ * W1_ * 4);
    float* dist1 = (float*)alloc((size_t)B_ * H1_ * W1_ * 4);
    float* ref2  = (float*)alloc((size_t)B_ * H2_ * W2_ * 4);
    float* dist2 = (float*)alloc((size_t)B_ * H2_ * W2_ * 4);
    float* ref3  = (float*)alloc((size_t)B_ * H3_ * W3_ * 4);
    float* dist3 = (float*)alloc((size_t)B_ * H3_ * W3_ * 4);

    double*   acc    = (double*)alloc(16 * sizeof(double2) + 64);
    unsigned* ticket = (unsigned*)((char*)acc + 16 * sizeof(double2));

    // Zero accumulators + ticket (ws is poisoned 0xAA before every timed call).
    hipMemsetAsync(acc, 0, 16 * sizeof(double2) + 64, stream);

    dim3 blk(256);

    // K1: stats<17>(L0) + down<9>(L0 -> L1)
    fused_kernel<17, 9, 0><<<dim3(N0_ + ND1_, 1, B_), blk, 0, stream>>>(
        ref, dist, H0_, W0_, 128.0f, acc, SY0,
        ref1, dist1, H1_, W1_, DGX1, N0_);

    // K2: stats<9>(L1) + down<5>(L1 -> L2)
    fused_kernel<9, 5, 1><<<dim3(N1_ + ND2_, 1, B_), blk, 0, stream>>>(
        ref1, dist1, H1_, W1_, 0.0f, acc, SY1,
        ref2, dist2, H2_, W2_, DGX2, N1_);

    // K3: stats<5>(L2) + down<3>(L2 -> L3)
    fused_kernel<5, 3, 2><<<dim3(N2_ + ND3_, 1, B_), blk, 0, stream>>>(
        ref2, dist2, H2_, W2_, 0.0f, acc, SY2,
        ref3, dist3, H3_, W3_, DGX3, N2_);

    // K4: stats<3>(L3) + ticket finalize (writes all 16 outputs)
    final_kernel<3><<<dim3(N3_, 1, B_), blk, 0, stream>>>(
        ref3, dist3, H3_, W3_, acc, ticket, SY3, N3_ * B_, out);
}

// Round 11
// 240.911 us; speedup vs baseline: 1.4018x; 1.4018x over previous
//
#include <hip/hip_runtime.h>
#include <math.h>

#define VIF_EPS       1e-10f
#define SIGMA_NSQ     2.0f
#define SIGMA_MAX_INV (4.0f / (255.0f * 255.0f))
#define GAIN_LIMIT    100.0f

// jnp.pad mode='reflect' (no edge duplication). Overshoot < dim, single reflection suffices.
__device__ __forceinline__ int reflect_idx(int i, int n) {
    i = (i < 0) ? -i : i;
    i = (i >= n) ? (2 * n - 2 - i) : i;
    return i;
}

// Reference: sigma=N/5; g=exp(-x^2/(2 sigma^2)); win=outer(g,g)/sum -> separable gn = g/sum(g).
// Thread-0 + LDS broadcast (R7-proven footprint; R9's all-lane expf raised VGPR 68->92).
template <int N>
__device__ __forceinline__ void compute_weights(float* wts) {
    if (threadIdx.x == 0) {
        const float sigma = (float)N / 5.0f;
        const float denom = 2.0f * sigma * sigma;
        float s = 0.0f;
        for (int i = 0; i < N; ++i) {
            float x = (float)i - (float)(N - 1) * 0.5f;
            float g = expf(-(x * x) / denom);
            wts[i] = g;
            s += g;
        }
        for (int i = 0; i < N; ++i) wts[i] = wts[i] / s;
    }
}

constexpr int tile_w(int N) { return (128 - (N - 1)) & ~3; }  // 17->112, 9->120, 5/3->124
constexpr int cdiv(int a, int b) { return (a + b - 1) / b; }

// ---- pyramid constants ----
constexpr int B_ = 4;
constexpr int H0_ = 1080, W0_ = 1920;
constexpr int H1_ = 540,  W1_ = 960;
constexpr int H2_ = 270,  W2_ = 480;
constexpr int H3_ = 135,  W3_ = 240;

constexpr int SX0 = cdiv(W0_, tile_w(17)), SY0 = cdiv(H0_, 8), N0_ = SX0 * SY0;  // 18x135
constexpr int SX1 = cdiv(W1_, tile_w(9)),  SY1 = cdiv(H1_, 8), N1_ = SX1 * SY1;  // 8x68
constexpr int SX2 = cdiv(W2_, tile_w(5)),  SY2 = cdiv(H2_, 8), N2_ = SX2 * SY2;  // 4x34
constexpr int SX3 = cdiv(W3_, tile_w(3)),  SY3 = cdiv(H3_, 8), N3_ = SX3 * SY3;  // 2x17

constexpr int DGX1 = W1_ / 120, ND1_ = DGX1 * cdiv(H1_, 8);  // 544
constexpr int DGX2 = W2_ / 120, ND2_ = DGX2 * cdiv(H2_, 8);  // 136
constexpr int DGX3 = W3_ / 120, ND3_ = DGX3 * cdiv(H3_, 8);  // 34

// ---- static shared layouts ----
template <int N>
struct StatsSmem {
    float v[5][8][132];   // row stride 528 B = 33*16 -> float4-clean
    float wts[N];
    float rsum[8];
};
template <int N>
struct DownSmem {
    float vb[2][8][252];
    float wts[N];
};

// ---------------- stats body (vertical-first separable VIF; R7-proven epilogue) ----------------
// bx flattened Y-MAJOR (ytile = bx % sy) for L2 reuse of vertical halos.
// Epilogue = deterministic per-block partial write. R10 lesson: per-block f64
// atomicAdd onto 4 hot lines cost ~90 us of serialized RMW drain — never again.
// VGPR discipline (~68): NO min-waves bound (R3 spill), 4-wide phase 2 (R5),
// no cross-phase unions (R8), no KY loop / per-thread expf (R9).
template <int N>
__device__ __forceinline__ void stats_body(
    StatsSmem<N>& sm, const float* __restrict__ refp, const float* __restrict__ distp,
    int h, int w, float shift, double2* __restrict__ partial,
    int sy, int sx, int bx, int b) {
    constexpr int P   = (N - 1) / 2;
    constexpr int VC  = 128;
    constexpr int TW  = tile_w(N);
    constexpr int TH  = 8;
    constexpr int Q   = 4;
    constexpr int LR  = Q + 2 * P;
    constexpr int XG  = TW / 4;
    constexpr int F4  = (N + 6) / 4;

    const int tid = threadIdx.x;
    const int ytile = bx % sy;
    const int xtile = bx / sy;
    const int x0 = xtile * TW;
    const int y0 = ytile * TH;

    compute_weights<N>(sm.wts);
    __syncthreads();

    float wr[N];
#pragma unroll
    for (int j = 0; j < N; ++j) wr[j] = sm.wts[j];

    // ---- Phase 1: vertical conv from global ----
    {
        const int c = tid & (VC - 1);
        const int g = tid >> 7;
        const int gx = reflect_idx(x0 + c - P, w);
        const float* rb = refp  + (size_t)b * h * w + gx;
        const float* db = distp + (size_t)b * h * w + gx;

        float acc[5][Q];
#pragma unroll
        for (int ch = 0; ch < 5; ++ch)
#pragma unroll
            for (int q = 0; q < Q; ++q) acc[ch][q] = 0.f;

        auto acc_push = [&](int i, float r, float d) {
            float p2 = r * r, p3 = d * d, p4 = r * d;
#pragma unroll
            for (int q = 0; q < Q; ++q) {
                int j = i - q;
                if (j >= 0 && j < N) {
                    float wj = wr[j];
                    acc[0][q] += wj * r;
                    acc[1][q] += wj * d;
                    acc[2][q] += wj * p2;
                    acc[3][q] += wj * p3;
                    acc[4][q] += wj * p4;
                }
            }
        };

        const int rowlo = y0 + g * Q - P;
        if (rowlo >= 0 && rowlo + LR <= h) {
            // Interior fast path (wave-uniform): pointer walk, no reflect per row.
            const float* pr = rb + (size_t)rowlo * w;
            const float* pd = db + (size_t)rowlo * w;
#pragma unroll
            for (int i = 0; i < LR; ++i) {
                float r = pr[0] - shift;
                float d = pd[0] - shift;
                pr += w; pd += w;
                acc_push(i, r, d);
            }
        } else {
#pragma unroll
            for (int i = 0; i < LR; ++i) {
                int gy = reflect_idx(rowlo + i, h);
                float r = rb[(size_t)gy * w] - shift;
                float d = db[(size_t)gy * w] - shift;
                acc_push(i, r, d);
            }
        }
#pragma unroll
        for (int ch = 0; ch < 5; ++ch)
#pragma unroll
            for (int q = 0; q < Q; ++q)
                sm.v[ch][g * Q + q][c] = acc[ch][q];
    }
    __syncthreads();

    // ---- Phase 2: horizontal conv + VIF math (4 outputs/thread) ----
    float num_v = 0.f, den_v = 0.f;
    {
        const int xg  = tid & 31;
        const int row = tid >> 5;
        if (xg < XG) {
            float mu[5][4];
#pragma unroll
            for (int ch = 0; ch < 5; ++ch) {
                float win[F4 * 4];
                const float4* s4 = (const float4*)&sm.v[ch][row][xg * 4];
#pragma unroll
                for (int f = 0; f < F4; ++f) {
                    float4 t = s4[f];
                    win[4 * f + 0] = t.x; win[4 * f + 1] = t.y;
                    win[4 * f + 2] = t.z; win[4 * f + 3] = t.w;
                }
#pragma unroll
                for (int q = 0; q < 4; ++q) {
                    float a = 0.f;
#pragma unroll
                    for (int j = 0; j < N; ++j) a += wr[j] * win[q + j];
                    mu[ch][q] = a;
                }
            }
            const int gy = y0 + row;
#pragma unroll
            for (int q = 0; q < 4; ++q) {
                int gx = x0 + xg * 4 + q;
                if (gx < w && gy < h) {
                    float mu1 = mu[0][q], mu2 = mu[1][q];
                    float s1  = fmaxf(0.f, mu[2][q] - mu1 * mu1);
                    float s2  = fmaxf(0.f, mu[3][q] - mu2 * mu2);
                    float s12 = mu[4][q] - mu1 * mu2;

                    float g  = s12 / (s1 + VIF_EPS);
                    float sv = s2 - g * s12;
                    if (s1 < VIF_EPS) { g = 0.f; sv = s2; s1 = 0.f; }
                    if (s2 < VIF_EPS) { g = 0.f; sv = 0.f; }
                    if (g  < 0.f)     { sv = s2; g = 0.f; }
                    if (sv <= VIF_EPS) sv = VIF_EPS;
                    g = fminf(g, GAIN_LIMIT);

                    float num_ar = __log2f(1.f + g * g * s1 / (sv + SIGMA_NSQ));
                    float den_ar = __log2f(1.f + s1 / SIGMA_NSQ);
                    if (s12 < 0.f) num_ar = 0.f;
                    if (s1 < SIGMA_NSQ) { num_ar = 1.f - s2 * SIGMA_MAX_INV; den_ar = 1.f; }
                    num_v += num_ar;
                    den_v += den_ar;
                }
            }
        }
    }

    // Block reduction -> deterministic per-block partial (no contended atomics).
#pragma unroll
    for (int off = 32; off > 0; off >>= 1) {
        num_v += __shfl_down(num_v, off);
        den_v += __shfl_down(den_v, off);
    }
    const int wid = tid >> 6, lane = tid & 63;
    if (lane == 0) { sm.rsum[wid] = num_v; sm.rsum[4 + wid] = den_v; }
    __syncthreads();
    if (tid == 0) {
        float ns = sm.rsum[0] + sm.rsum[1] + sm.rsum[2] + sm.rsum[3];
        float ds = sm.rsum[4] + sm.rsum[5] + sm.rsum[6] + sm.rsum[7];
        partial[(size_t)b * (sy * sx) + bx] = make_double2((double)ns, (double)ds);
    }
}

// ---------------- downsample body: vertical-first, 120x8 output tile (R7-proven) ----------------
template <int N>
__device__ __forceinline__ void down_body(
    DownSmem<N>& sm, const float* __restrict__ rin, const float* __restrict__ din,
    float* __restrict__ rout, float* __restrict__ dout,
    int h, int w, int h2, int w2, float shift, int dgx, int bx, int b) {
    constexpr int P   = (N - 1) / 2;
    constexpr int TOW = 120, TOH = 8;
    constexpr int IC  = 2 * (TOW - 1) + N;
    constexpr int NR  = 2 * (TOH - 1) + N;
    constexpr int XGn = TOW / 8;
    constexpr int WL  = 14 + N;
    constexpr int F4n = (WL + 3) / 4;

    compute_weights<N>(sm.wts);
    __syncthreads();

    float wr[N];
#pragma unroll
    for (int j = 0; j < N; ++j) wr[j] = sm.wts[j];

    const int tid = threadIdx.x;
    const int xt  = bx % dgx;
    const int yt  = bx / dgx;
    const int x0  = xt * TOW;
    const int y0  = yt * TOH;

    // ---- Vertical decimating pass ----
    if (tid < IC) {
        const int gx = reflect_idx(2 * x0 - P + tid, w);
        const int rowlo = 2 * y0 - P;
        const bool interior = (rowlo >= 0) && (rowlo + NR <= h);
#pragma unroll
        for (int img = 0; img < 2; ++img) {
            const float* src = (img ? din : rin) + (size_t)b * h * w + gx;
            float rows[NR];
            if (interior) {
                const float* p = src + (size_t)rowlo * w;
#pragma unroll
                for (int i = 0; i < NR; ++i) { rows[i] = p[0] - shift; p += w; }
            } else {
#pragma unroll
                for (int i = 0; i < NR; ++i)
                    rows[i] = src[(size_t)reflect_idx(rowlo + i, h) * w] - shift;
            }
#pragma unroll
            for (int t = 0; t < TOH; ++t) {
                float a = 0.f;
#pragma unroll
                for (int j = 0; j < N; ++j) a += wr[j] * rows[2 * t + j];
                sm.vb[img][t][tid] = a;
            }
        }
    }
    __syncthreads();

    // ---- Horizontal decimating pass ----
    if (tid < 2 * TOH * XGn) {
        const int img = tid / (TOH * XGn);
        const int rem = tid - img * (TOH * XGn);
        const int row = rem / XGn;
        const int xg  = rem - row * XGn;

        float win[F4n * 4];
        const float4* s4 = (const float4*)&sm.vb[img][row][16 * xg];
#pragma unroll
        for (int f = 0; f < F4n; ++f) {
            float4 t = s4[f];
            win[4 * f + 0] = t.x; win[4 * f + 1] = t.y;
            win[4 * f + 2] = t.z; win[4 * f + 3] = t.w;
        }
        float o[8];
#pragma unroll
        for (int q = 0; q < 8; ++q) {
            float a = 0.f;
#pragma unroll
            for (int j = 0; j < N; ++j) a += wr[j] * win[2 * q + j];
            o[q] = a;
        }
        const int gy = y0 + row;
        if (gy < h2) {
            float* outp = (img ? dout : rout) + (size_t)b * h2 * w2
                        + (size_t)gy * w2 + x0 + 8 * xg;
            *(float4*)outp       = make_float4(o[0], o[1], o[2], o[3]);
            *(float4*)(outp + 4) = make_float4(o[4], o[5], o[6], o[7]);
        }
    }
}

// ---------------- kernels ----------------
template <int NS, int ND>
__global__ __launch_bounds__(256) void fused_kernel(
    const float* __restrict__ sref, const float* __restrict__ sdist,
    int sh, int sw, float sshift, double2* __restrict__ partial, int sy, int sx,
    float* __restrict__ drout, float* __restrict__ ddout,
    int dh2, int dw2, int dgx, int nStats) {
    __shared__ union {
        StatsSmem<NS> s;
        DownSmem<ND>  d;
    } u;
    const int bx = blockIdx.x;
    const int b  = blockIdx.z;
    if (bx < nStats)
        stats_body<NS>(u.s, sref, sdist, sh, sw, sshift, partial, sy, sx, bx, b);
    else
        down_body<ND>(u.d, sref, sdist, drout, ddout, sh, sw, dh2, dw2, sshift, dgx,
                      bx - nStats, b);
}

// K4: stats<3> writes its partial; ticket picks a winner block which reduces ALL
// partials (deterministic per-group order) and writes the 16 outputs.
template <int N>
__global__ __launch_bounds__(256) void final_kernel(
    const float* __restrict__ refp, const float* __restrict__ distp,
    int h, int w, double2* __restrict__ part, unsigned* __restrict__ ticket,
    int sy, int sx, int nTickets, float* __restrict__ out) {
    __shared__ StatsSmem<N> sm;
    __shared__ double dsum[8];
    __shared__ int winner;
    const int b = blockIdx.z;
    stats_body<N>(sm, refp, distp, h, w, 0.0f,
                  part + B_ * (N0_ + N1_ + N2_), sy, sx, blockIdx.x, b);

    if (threadIdx.x == 0) {
        __threadfence();
        unsigned old = atomicAdd(ticket, 1u);
        winner = (old == (unsigned)(nTickets - 1)) ? 1 : 0;
    }
    __syncthreads();
    if (!winner) return;
    __threadfence();  // acquire: see all partial writes

    constexpr int RBASE[4] = {0, B_ * N0_, B_ * (N0_ + N1_), B_ * (N0_ + N1_ + N2_)};
    constexpr int RCNT[4]  = {N0_, N1_, N2_, N3_};
    const int tid = threadIdx.x;
    for (int grp = 0; grp < 16; ++grp) {
        const int s  = grp & 3;
        const int bb = grp >> 2;
        const double2* p = part + RBASE[s] + (size_t)bb * RCNT[s];
        double ns = 0.0, ds = 0.0;
        for (int i = tid; i < RCNT[s]; i += 256) {
            double2 v = p[i];
            ns += v.x;
            ds += v.y;
        }
#pragma unroll
        for (int off = 32; off > 0; off >>= 1) {
            ns += __shfl_down(ns, off);
            ds += __shfl_down(ds, off);
        }
        const int wid = tid >> 6, lane = tid & 63;
        if (lane == 0) { dsum[wid] = ns; dsum[4 + wid] = ds; }
        __syncthreads();
        if (tid == 0) {
            double Nv = dsum[0] + dsum[1] + dsum[2] + dsum[3];
            double Dv = dsum[4] + dsum[5] + dsum[6] + dsum[7];
            out[bb * 4 + s] = (float)(Nv / Dv);
        }
        __syncthreads();
    }
}

extern "C" void kernel_launch(void* const* d_in, const int* in_sizes, int n_in,
                              void* d_out, int out_size, void* d_ws, size_t ws_size,
                              hipStream_t stream) {
    const float* ref  = (const float*)d_in[0];
    const float* dist = (const float*)d_in[1];
    float* out = (float*)d_out;

    char*  ws  = (char*)d_ws;
    size_t off = 0;
    auto alloc = [&](size_t bytes) -> void* {
        void* p = ws + off;
        off += (bytes + 255) & ~(size_t)255;
        return p;
    };
    float* ref1  = (float*)alloc((size_t)B_ * H1_ * W1_ * 4);
    float* dist1 = (float*)alloc((size_t)B_ * H1_ * W1_ * 4);
    float* ref2  = (float*)alloc((size_t)B_ * H2_ * W2_ * 4);
    float* dist2 = (float*)alloc((size_t)B_ * H2_ * W2_ * 4);
    float* ref3  = (float*)alloc((size_t)B_ * H3_ * W3_ * 4);
    float* dist3 = (float*)alloc((size_t)B_ * H3_ * W3_ * 4);

    double2*  part   = (double2*)alloc((size_t)B_ * (N0_ + N1_ + N2_ + N3_) * sizeof(double2));
    unsigned* ticket = (unsigned*)alloc(256);

    // Zero the ticket only (partials are fully written before being read).
    hipMemsetAsync(ticket, 0, 4, stream);

    dim3 blk(256);
    double2* p0 = part;
    double2* p1 = p0 + B_ * N0_;
    double2* p2 = p1 + B_ * N1_;

    // K1: stats<17>(L0) + down<9>(L0 -> L1)
    fused_kernel<17, 9><<<dim3(N0_ + ND1_, 1, B_), blk, 0, stream>>>(
        ref, dist, H0_, W0_, 128.0f, p0, SY0, SX0,
        ref1, dist1, H1_, W1_, DGX1, N0_);

    // K2: stats<9>(L1) + down<5>(L1 -> L2)
    fused_kernel<9, 5><<<dim3(N1_ + ND2_, 1, B_), blk, 0, stream>>>(
        ref1, dist1, H1_, W1_, 0.0f, p1, SY1, SX1,
        ref2, dist2, H2_, W2_, DGX2, N1_);

    // K3: stats<5>(L2) + down<3>(L2 -> L3)
    fused_kernel<5, 3><<<dim3(N2_ + ND3_, 1, B_), blk, 0, stream>>>(
        ref2, dist2, H2_, W2_, 0.0f, p2, SY2, SX2,
        ref3, dist3, H3_, W3_, DGX3, N2_);

    // K4: stats<3>(L3) + ticket winner reduces all partials, writes 16 outputs
    final_kernel<3><<<dim3(N3_, 1, B_), blk, 0, stream>>>(
        ref3, dist3, H3_, W3_, part, ticket, SY3, SX3, N3_ * B_, out);
}